// Round 2
// baseline (92.780 us; speedup 1.0000x reference)
//
#include <hip/hip_runtime.h>

// VQC: NQ=4 qubits, NL=1 layer, B=1048576.
// Single fused kernel:
//  - threads 0-3 compute per-qubit U3 measurement constants from the 12
//    uniform weights into LDS (phi provably drops out of <Z_q>; U3 on
//    qubits != q commutes with Z_q, so only qubit-q's theta/lambda matter).
//  - all 256 threads stage the block's 768 enc float4s through LDS with
//    perfectly coalesced loads (stride-12-dword readback is conflict-free:
//    12*i mod 32 covers all 32 banks across every 8 lanes).
//  - per element: product state ⊗_q RZ·RY·RZ|+> (2 cplx amps/qubit),
//    tensor-expand to 16 amps, CNOT chain = compile-time register
//    permutation, fused U3+Z measurement:
//      z_q = Σ_pairs alpha_q (p_i - p_j) + g1_q Re(a_i ā_j) + g2_q Im(a_i ā_j)

__global__ __launch_bounds__(256) void vqc_fused(const float4* __restrict__ enc,
                                                 const float* __restrict__ w,
                                                 float4* __restrict__ out, int B) {
    __shared__ float4 stage[768];
    __shared__ float4 wc[4];

    const int tid  = threadIdx.x;
    const int base = blockIdx.x * 256;          // first batch element of block
    const long gbase = (long)base * 3;          // float4 index into enc

    // coalesced stage: 3 x (256 lanes x 16B contiguous)
#pragma unroll
    for (int k = 0; k < 3; ++k) {
        long gi = gbase + tid + 256 * k;
        if (gi < (long)B * 3) stage[tid + 256 * k] = enc[gi];
    }

    if (tid < 4) {
        const int q = tid;
        float th = w[q * 3 + 0];
        float lm = w[q * 3 + 2];
        float s, c, sl, cl;
        __sincosf(0.5f * th, &s, &c);
        __sincosf(lm, &sl, &cl);
        // alpha = c^2-s^2 ; gamma = -2cs e^{-i lm} ; contribs use 2*gamma
        wc[q] = make_float4(c * c - s * s, -4.0f * c * s * cl, -4.0f * c * s * sl, 0.0f);
    }
    __syncthreads();

    const int b = base + tid;
    if (b >= B) return;

    float4 e0 = stage[3 * tid + 0];
    float4 e1 = stage[3 * tid + 1];
    float4 e2 = stage[3 * tid + 2];
    float ang[12] = {e0.x, e0.y, e0.z, e0.w, e1.x, e1.y, e1.z, e1.w,
                     e2.x, e2.y, e2.z, e2.w};

    // per-qubit encoded state v[q] = RZ(g) RY(bt) RZ(a) |+>
    float vx[4][2], vy[4][2];
    const float inv = 0.70710678118654752f;
#pragma unroll
    for (int q = 0; q < 4; ++q) {
        float sa, ca, sb, cb, sg, cg;
        __sincosf(0.5f * ang[3 * q + 0], &sa, &ca);
        __sincosf(0.5f * ang[3 * q + 1], &sb, &cb);
        __sincosf(0.5f * ang[3 * q + 2], &sg, &cg);
        float P = cb - sb, Q = cb + sb;
        float y0x = ca * P * inv, y0y = -sa * Q * inv;
        float y1x = ca * Q * inv, y1y = sa * P * inv;
        vx[q][0] = cg * y0x + sg * y0y;   // e^{-i g/2} * y0
        vy[q][0] = cg * y0y - sg * y0x;
        vx[q][1] = cg * y1x - sg * y1y;   // e^{+i g/2} * y1
        vy[q][1] = cg * y1y + sg * y1x;
    }

    // tensor product halves: u = v0 (x) v1, wv = v2 (x) v3
    float ux[4], uy[4], wxx[4], wyy[4];
#pragma unroll
    for (int i = 0; i < 2; ++i)
#pragma unroll
        for (int j = 0; j < 2; ++j) {
            ux[i * 2 + j]  = vx[0][i] * vx[1][j] - vy[0][i] * vy[1][j];
            uy[i * 2 + j]  = vx[0][i] * vy[1][j] + vy[0][i] * vx[1][j];
            wxx[i * 2 + j] = vx[2][i] * vx[3][j] - vy[2][i] * vy[3][j];
            wyy[i * 2 + j] = vx[2][i] * vy[3][j] + vy[2][i] * vx[3][j];
        }

    // full 16-amp state: idx = q0*8 + q1*4 + q2*2 + q3
    float ax[16], ay[16];
#pragma unroll
    for (int h = 0; h < 4; ++h)
#pragma unroll
        for (int l = 0; l < 4; ++l) {
            ax[h * 4 + l] = ux[h] * wxx[l] - uy[h] * wyy[l];
            ay[h * 4 + l] = ux[h] * wyy[l] + uy[h] * wxx[l];
        }

    // CNOT chain (0,1),(1,2),(2,3),(3,0): compile-time register permutation
    const int cm[4] = {8, 4, 2, 1};
    const int tm[4] = {4, 2, 1, 8};
#pragma unroll
    for (int k = 0; k < 4; ++k) {
#pragma unroll
        for (int i = 0; i < 16; ++i) {
            if ((i & cm[k]) && !(i & tm[k])) {
                int j = i | tm[k];
                float tx = ax[i], ty = ay[i];
                ax[i] = ax[j]; ay[i] = ay[j];
                ax[j] = tx;    ay[j] = ty;
            }
        }
    }

    float p[16];
#pragma unroll
    for (int i = 0; i < 16; ++i) p[i] = ax[i] * ax[i] + ay[i] * ay[i];

    float4 w0 = wc[0], w1 = wc[1], w2 = wc[2], w3 = wc[3];
    float al[4] = {w0.x, w1.x, w2.x, w3.x};
    float g1[4] = {w0.y, w1.y, w2.y, w3.y};
    float g2[4] = {w0.z, w1.z, w2.z, w3.z};

    float z[4];
#pragma unroll
    for (int q = 0; q < 4; ++q) {
        int m = 8 >> q;
        float acc = 0.0f;
#pragma unroll
        for (int i = 0; i < 16; ++i) {
            if (!(i & m)) {
                int j = i | m;
                float cx = ax[i] * ax[j] + ay[i] * ay[j];
                float cy = ay[i] * ax[j] - ax[i] * ay[j];
                acc += al[q] * (p[i] - p[j]) + g1[q] * cx + g2[q] * cy;
            }
        }
        z[q] = acc;
    }

    out[b] = make_float4(z[0], z[1], z[2], z[3]);
}

extern "C" void kernel_launch(void* const* d_in, const int* in_sizes, int n_in,
                              void* d_out, int out_size, void* d_ws, size_t ws_size,
                              hipStream_t stream) {
    const float* enc = (const float*)d_in[0];   // (B, 4, 3) f32
    const float* w   = (const float*)d_in[1];   // (1, 4, 3) f32
    float* out = (float*)d_out;                 // (B, 4) f32

    int B = in_sizes[0] / 12;
    int grid = (B + 255) / 256;
    vqc_fused<<<grid, 256, 0, stream>>>((const float4*)enc, w, (float4*)out, B);
}